// Round 2
// baseline (952.574 us; speedup 1.0000x reference)
//
#include <hip/hip_runtime.h>

// JBF block: M = 2*16*128*128 = 524288 voxels, 125-float (500 B) dom/gui record each.
// v3: occupancy fix. Stage records in FOUR 32-float column-phases through an 8 KB
// LDS buffer (was one 32 KB chunk -> 5 blocks/CU). LDS layout [v][32] linear so
// dword-granule global_load_lds works (records are only 4B-aligned, so 16B variant
// is illegal); read conflicts avoided by XOR-swizzling the SOURCE f-offset with
// (v&31) and reading col (c ^ (lane&31)) -> bank = (c^lane)&31, conflict-free.
// f=124 (the odd float out) hits only acc[26] and is a per-lane register load.

#define VPB 64          // voxels per block == block size (1 wave)
#define REC 125         // floats per record

#define GAS(p) ((const __attribute__((address_space(1))) float*)(p))
#define LAS(p) ((__attribute__((address_space(3))) float*)(p))

// Stage floats [F0, F0+32) of all 64 records into lds[64][32] (linear dwords).
// Physical slot s of record v holds global float F0 + (s ^ (v&31)).
// Instr k writes LDS dwords [k*64, k*64+64) = records 2k (lanes 0..31) and
// 2k+1 (lanes 32..63); each 32-lane half covers one record's full 128 B window
// (XOR permutes within the window) -> ~2-4 cache lines per instruction.
template <int F0>
__device__ __forceinline__ void stage32(const float* __restrict__ src, int m0,
                                        float* lds, int lane)
{
    const int half = lane >> 5;   // which record of the pair this lane serves
    const int sl   = lane & 31;   // physical slot within the record's 32 cols
#pragma unroll
    for (int k = 0; k < 32; ++k) {
        const int v = 2 * k + half;
        int fo = sl ^ ((2 * k) & 31) ^ half;        // sl ^ (v&31)
        if (F0 == 96) fo = fo < 27 ? fo : 27;       // f>=124 invalid: dup slot, never read
        const float* g = src + (size_t)(m0 + v) * REC + F0 + fo;
        __builtin_amdgcn_global_load_lds(GAS(g), LAS(lds + k * 64), 4, 0, 0);
    }
}

// Accumulate conv contributions of floats [F0, min(F0+32,124)) from the staged
// buffer. Read of logical col c is physical col c ^ (lane&31) (matches staging).
template <int F0>
__device__ __forceinline__ void conv_part(const float* __restrict__ sbuf, int lane,
                                          const float* __restrict__ w, float* acc)
{
    const int xs   = lane & 31;
    const int base = lane * 32;
#pragma unroll
    for (int c0 = 0; c0 < 32; ++c0) {
        const int f = F0 + c0;
        if (f >= 124) continue;                 // f==124 handled in registers
        const float v = sbuf[base + (c0 ^ xs)];
        const int z  = f / 25;
        const int r  = (f % 25) / 5;
        const int c5 = f % 5;
#pragma unroll
        for (int i = 0; i < 3; ++i) {
            const int a = z - i; if (a < 0 || a > 2) continue;
#pragma unroll
            for (int j = 0; j < 3; ++j) {
                const int b = r - j; if (b < 0 || b > 2) continue;
#pragma unroll
                for (int l = 0; l < 3; ++l) {
                    const int cc = c5 - l; if (cc < 0 || cc > 2) continue;
                    acc[(i * 3 + j) * 3 + l] =
                        fmaf(v, w[(a * 3 + b) * 3 + cc], acc[(i * 3 + j) * 3 + l]);
                }
            }
        }
    }
}

__global__ __launch_bounds__(64, 4) void jbf_kernel(
    const float* __restrict__ x,      // [2,1,18,128,128]
    const float* __restrict__ dom,    // [M,125]
    const float* __restrict__ gui,    // [M,125]
    const float* __restrict__ dom_w,  // [27]
    const float* __restrict__ dom_b,  // [1]
    const float* __restrict__ rng_w,  // [27]
    const float* __restrict__ rng_b,  // [1]
    float* __restrict__ out)          // [M]
{
    __shared__ float sm[VPB * 32];    // 8192 B -> up to 20 blocks/CU (was 32 KB -> 5)
    const int lane = threadIdx.x;
    const int m0   = blockIdx.x * VPB;
    const int m    = m0 + lane;

    const float bd = dom_b[0], br = rng_b[0];

    // f=124 never tiles into 32-float phases; it only feeds acc[26]
    // ((z,r,c)=(4,4,4) -> single valid output (2,2,2)). Per-lane register load.
    const float d124 = dom[(size_t)m * REC + 124];
    const float g124 = gui[(size_t)m * REC + 124];

    float dkv[27], acc[27];

    // One code instance for both convs (I-cache): p=0 dom->dkv, p=1 gui->acc.
#pragma unroll 1
    for (int p = 0; p < 2; ++p) {
        const float* __restrict__ src  = p ? gui : dom;
        const float* __restrict__ wsrc = p ? rng_w : dom_w;  // uniform -> scalar loads
        float w[27];
#pragma unroll
        for (int i = 0; i < 27; ++i) w[i] = wsrc[i];
#pragma unroll
        for (int i = 0; i < 27; ++i) acc[i] = 0.f;

        stage32<0>(src, m0, sm, lane);
        __syncthreads();                       // drains gl_lds (vmcnt) + visibility
        conv_part<0>(sm, lane, w, acc);
        __syncthreads();                       // reads done before restage

        stage32<32>(src, m0, sm, lane);
        __syncthreads();
        conv_part<32>(sm, lane, w, acc);
        __syncthreads();

        stage32<64>(src, m0, sm, lane);
        __syncthreads();
        conv_part<64>(sm, lane, w, acc);
        __syncthreads();

        stage32<96>(src, m0, sm, lane);
        __syncthreads();
        conv_part<96>(sm, lane, w, acc);
        __syncthreads();

        // f=124 term last, preserving original ascending-f accumulation order
        acc[26] = fmaf(p ? g124 : d124, w[26], acc[26]);

        if (p == 0) {
#pragma unroll
            for (int i = 0; i < 27; ++i) dkv[i] = acc[i];
        }
    }
    // here: dkv = dom conv, acc = gui conv

    // ---- epilogue: weights * x-neighborhood, normalize (unchanged) ----
    // m = ((b*16 + dz)*128 + h)*128 + w
    const int w_ = m & 127;
    const int h_ = (m >> 7) & 127;
    const int dz = (m >> 14) & 15;
    const int b_ = m >> 18;

    float num = 0.f, den = 0.f;
#pragma unroll
    for (int i = 0; i < 3; ++i) {
        const int zz = b_ * 18 + dz + i;   // depth always in range
#pragma unroll
        for (int j = 0; j < 3; ++j) {
            const int hh = h_ - 1 + j;
            const bool okh = (unsigned)hh < 128u;
#pragma unroll
            for (int l = 0; l < 3; ++l) {
                const int ww = w_ - 1 + l;
                const bool ok = okh && ((unsigned)ww < 128u);
                const float xv = ok ? x[((size_t)zz * 128 + hh) * 128 + ww] : 0.f;
                const float wv = fmaxf(dkv[(i * 3 + j) * 3 + l] + bd, 0.f) *
                                 fmaxf(acc[(i * 3 + j) * 3 + l] + br, 0.f) + 1e-10f;
                den += wv;
                num = fmaf(wv, xv, num);
            }
        }
    }
    out[m] = num / den;
}

extern "C" void kernel_launch(void* const* d_in, const int* in_sizes, int n_in,
                              void* d_out, int out_size, void* d_ws, size_t ws_size,
                              hipStream_t stream) {
    const float* x     = (const float*)d_in[0];
    const float* dom   = (const float*)d_in[1];
    const float* gui   = (const float*)d_in[2];
    const float* dom_w = (const float*)d_in[3];
    const float* dom_b = (const float*)d_in[4];
    const float* rng_w = (const float*)d_in[5];
    const float* rng_b = (const float*)d_in[6];
    float* outp = (float*)d_out;

    const int M = in_sizes[1] / REC;      // 524288
    const int grid = M / VPB;             // 8192 blocks
    jbf_kernel<<<grid, VPB, 0, stream>>>(x, dom, gui, dom_w, dom_b,
                                         rng_w, rng_b, outp);
}

// Round 3
// 522.042 us; speedup vs baseline: 1.8247x; 1.8247x over previous
//
#include <hip/hip_runtime.h>

// JBF block: M = 2*16*128*128 = 524288 voxels, 125-float (500 B) dom/gui record each.
// v4 = v3 structure (8 KB phased LDS staging, occupancy fix) with the spill bug fixed:
// __launch_bounds__(64,4) made the allocator target 64 VGPRs and spill dkv/acc to
// scratch (WRITE_SIZE 2MB -> 880MB, VALUBusy 15 -> 4.9). Plain __launch_bounds__(64)
// (the zero-spill 144-VGPR baseline setting) restores register residency; LDS stays
// 8 KB so occupancy is VGPR-limited at ~12 waves/CU instead of LDS-limited at 5.
//
// Staging: records are 500 B (4B-aligned) so only the dword-granule
// global_load_lds applies. LDS layout [v][32] linear (gl_lds dest must be
// uniform-base + lane*4); bank conflicts on the stride-32 reads avoided by
// XOR-swizzling the SOURCE float offset with (v&31) and reading col
// (c ^ (lane&31)) -> bank = (c^lane)&31, conflict-free (2 lanes/bank, free).
// f=124 (the odd float out of 4x32) only feeds acc[26]; per-lane register load.

#define VPB 64          // voxels per block == block size (1 wave)
#define REC 125         // floats per record

#define GAS(p) ((const __attribute__((address_space(1))) float*)(p))
#define LAS(p) ((__attribute__((address_space(3))) float*)(p))

// Stage floats [F0, F0+32) of all 64 records into lds[64][32] (linear dwords).
// Physical slot s of record v holds global float F0 + (s ^ (v&31)).
// Instr k writes LDS dwords [k*64, k*64+64) = records 2k (lanes 0..31) and
// 2k+1 (lanes 32..63); each 32-lane half covers one record's full 128 B window
// (XOR permutes within the window) -> 2-3 cache lines per half.
template <int F0>
__device__ __forceinline__ void stage32(const float* __restrict__ src, int m0,
                                        float* lds, int lane)
{
    const int half = lane >> 5;   // which record of the pair this lane serves
    const int sl   = lane & 31;   // physical slot within the record's 32 cols
#pragma unroll
    for (int k = 0; k < 32; ++k) {
        const int v = 2 * k + half;
        int fo = sl ^ ((2 * k) & 31) ^ half;        // sl ^ (v&31)
        if (F0 == 96) fo = fo < 27 ? fo : 27;       // f>=124 invalid: dup slot, never read
        const float* g = src + (size_t)(m0 + v) * REC + F0 + fo;
        __builtin_amdgcn_global_load_lds(GAS(g), LAS(lds + k * 64), 4, 0, 0);
    }
}

// Accumulate conv contributions of floats [F0, min(F0+32,124)) from the staged
// buffer. Read of logical col c is physical col c ^ (lane&31) (matches staging).
template <int F0>
__device__ __forceinline__ void conv_part(const float* __restrict__ sbuf, int lane,
                                          const float* __restrict__ w, float* acc)
{
    const int xs   = lane & 31;
    const int base = lane * 32;
#pragma unroll
    for (int c0 = 0; c0 < 32; ++c0) {
        const int f = F0 + c0;
        if (f >= 124) continue;                 // f==124 handled in registers
        const float v = sbuf[base + (c0 ^ xs)];
        const int z  = f / 25;
        const int r  = (f % 25) / 5;
        const int c5 = f % 5;
#pragma unroll
        for (int i = 0; i < 3; ++i) {
            const int a = z - i; if (a < 0 || a > 2) continue;
#pragma unroll
            for (int j = 0; j < 3; ++j) {
                const int b = r - j; if (b < 0 || b > 2) continue;
#pragma unroll
                for (int l = 0; l < 3; ++l) {
                    const int cc = c5 - l; if (cc < 0 || cc > 2) continue;
                    acc[(i * 3 + j) * 3 + l] =
                        fmaf(v, w[(a * 3 + b) * 3 + cc], acc[(i * 3 + j) * 3 + l]);
                }
            }
        }
    }
}

__global__ __launch_bounds__(64) void jbf_kernel(
    const float* __restrict__ x,      // [2,1,18,128,128]
    const float* __restrict__ dom,    // [M,125]
    const float* __restrict__ gui,    // [M,125]
    const float* __restrict__ dom_w,  // [27]
    const float* __restrict__ dom_b,  // [1]
    const float* __restrict__ rng_w,  // [27]
    const float* __restrict__ rng_b,  // [1]
    float* __restrict__ out)          // [M]
{
    __shared__ float sm[VPB * 32];    // 8192 B
    const int lane = threadIdx.x;
    const int m0   = blockIdx.x * VPB;
    const int m    = m0 + lane;

    const float bd = dom_b[0], br = rng_b[0];

    // f=124 never tiles into 32-float phases; it only feeds acc[26]
    // ((z,r,c)=(4,4,4) -> single valid output (2,2,2)). Per-lane register load.
    const float d124 = dom[(size_t)m * REC + 124];
    const float g124 = gui[(size_t)m * REC + 124];

    float dkv[27], acc[27];

    // One code instance for both convs (I-cache): p=0 dom->dkv, p=1 gui->acc.
#pragma unroll 1
    for (int p = 0; p < 2; ++p) {
        const float* __restrict__ src  = p ? gui : dom;
        const float* __restrict__ wsrc = p ? rng_w : dom_w;  // uniform -> scalar loads
        float w[27];
#pragma unroll
        for (int i = 0; i < 27; ++i) w[i] = wsrc[i];
#pragma unroll
        for (int i = 0; i < 27; ++i) acc[i] = 0.f;

        stage32<0>(src, m0, sm, lane);
        __syncthreads();                       // drains gl_lds (vmcnt) + visibility
        conv_part<0>(sm, lane, w, acc);
        __syncthreads();                       // reads done before restage

        stage32<32>(src, m0, sm, lane);
        __syncthreads();
        conv_part<32>(sm, lane, w, acc);
        __syncthreads();

        stage32<64>(src, m0, sm, lane);
        __syncthreads();
        conv_part<64>(sm, lane, w, acc);
        __syncthreads();

        stage32<96>(src, m0, sm, lane);
        __syncthreads();
        conv_part<96>(sm, lane, w, acc);
        __syncthreads();

        // f=124 term last, preserving original ascending-f accumulation order
        acc[26] = fmaf(p ? g124 : d124, w[26], acc[26]);

        if (p == 0) {
#pragma unroll
            for (int i = 0; i < 27; ++i) dkv[i] = acc[i];
        }
    }
    // here: dkv = dom conv, acc = gui conv

    // ---- epilogue: weights * x-neighborhood, normalize (unchanged) ----
    // m = ((b*16 + dz)*128 + h)*128 + w
    const int w_ = m & 127;
    const int h_ = (m >> 7) & 127;
    const int dz = (m >> 14) & 15;
    const int b_ = m >> 18;

    float num = 0.f, den = 0.f;
#pragma unroll
    for (int i = 0; i < 3; ++i) {
        const int zz = b_ * 18 + dz + i;   // depth always in range
#pragma unroll
        for (int j = 0; j < 3; ++j) {
            const int hh = h_ - 1 + j;
            const bool okh = (unsigned)hh < 128u;
#pragma unroll
            for (int l = 0; l < 3; ++l) {
                const int ww = w_ - 1 + l;
                const bool ok = okh && ((unsigned)ww < 128u);
                const float xv = ok ? x[((size_t)zz * 128 + hh) * 128 + ww] : 0.f;
                const float wv = fmaxf(dkv[(i * 3 + j) * 3 + l] + bd, 0.f) *
                                 fmaxf(acc[(i * 3 + j) * 3 + l] + br, 0.f) + 1e-10f;
                den += wv;
                num = fmaf(wv, xv, num);
            }
        }
    }
    out[m] = num / den;
}

extern "C" void kernel_launch(void* const* d_in, const int* in_sizes, int n_in,
                              void* d_out, int out_size, void* d_ws, size_t ws_size,
                              hipStream_t stream) {
    const float* x     = (const float*)d_in[0];
    const float* dom   = (const float*)d_in[1];
    const float* gui   = (const float*)d_in[2];
    const float* dom_w = (const float*)d_in[3];
    const float* dom_b = (const float*)d_in[4];
    const float* rng_w = (const float*)d_in[5];
    const float* rng_b = (const float*)d_in[6];
    float* outp = (float*)d_out;

    const int M = in_sizes[1] / REC;      // 524288
    const int grid = M / VPB;             // 8192 blocks
    jbf_kernel<<<grid, VPB, 0, stream>>>(x, dom, gui, dom_w, dom_b,
                                         rng_w, rng_b, outp);
}